// Round 4
// baseline (10465.633 us; speedup 1.0000x reference)
//
#include <hip/hip_runtime.h>

#define NGF 256     // dst-regions (span = ceil(N/256) <= SPANMAX)
#define NBMAX 2048  // max bucket blocks (E <= 4.19M)
#define CSTR 64     // colsum element stride (256B) -> spread across L2 slices
#define TS 1024     // src-tile rows for conv streaming (16B/row per plane = 16KB tile)
#define NT_MAX 112  // >= ceil(N/TS)
#define SPANMAX 400
#define NGG 4       // epilogue 128-node groups: NGG*128 >= SPANMAX
#define CONV_T 512  // conv threads (8 waves)

typedef float    f2 __attribute__((ext_vector_type(2)));
typedef float    f4 __attribute__((ext_vector_type(4)));
typedef float    f8 __attribute__((ext_vector_type(8)));
typedef _Float16 h8 __attribute__((ext_vector_type(8)));

__device__ __forceinline__ unsigned f2key(float x){
  unsigned b = __float_as_uint(x);
  return (b & 0x80000000u) ? ~b : (b | 0x80000000u);
}
__device__ __forceinline__ float key2f(unsigned k){
  return (k & 0x80000000u) ? __uint_as_float(k ^ 0x80000000u) : __uint_as_float(~k);
}

// fp8 e4m3 HW decode
__device__ __forceinline__ f4 dec4(unsigned w){
  f2 a = __builtin_amdgcn_cvt_pk_f32_fp8((int)w, false);
  f2 b = __builtin_amdgcn_cvt_pk_f32_fp8((int)w, true);
  f4 r; r[0]=a[0]; r[1]=a[1]; r[2]=b[0]; r[3]=b[1];
  return r;
}
__device__ __forceinline__ f8 dec8(uint2 w){
  f4 lo = dec4(w.x), hi = dec4(w.y);
  f8 r;
  r[0]=lo[0]; r[1]=lo[1]; r[2]=lo[2]; r[3]=lo[3];
  r[4]=hi[0]; r[5]=hi[1]; r[6]=hi[2]; r[7]=hi[3];
  return r;
}

// LDS-only barrier: drain this wave's LDS ops + rendezvous, WITHOUT draining vmcnt,
// so global prefetch loads stay in flight across the barrier. sched_barrier pins
// the compiler (rule: inline-asm waitcnt alone doesn't stop motion).
#define BAR_LDS() do{ asm volatile("s_waitcnt lgkmcnt(0)" ::: "memory"); \
                      __builtin_amdgcn_s_barrier(); \
                      __builtin_amdgcn_sched_barrier(0); }while(0)

// ---------------- CSR build (R14, measured-good): zero per-edge global atomics ----------------
// pack: val = (dl<<17)|src  (dl < 512, src < 131072)

__global__ __launch_bounds__(256) void k_bucketA(const int* __restrict__ ei,
    int* __restrict__ bucket, int* __restrict__ lbasemat,
    int E, int n, int span, unsigned magic){
  __shared__ int lcnt[NGF];
  __shared__ int lbase[NGF+1];
  __shared__ int sStage[2048];
  __shared__ int sScan[256];
  int tid = threadIdx.x;
  lcnt[tid] = 0;
  __syncthreads();
  int base = blockIdx.x*2048;
  int val[8], meta[8];
  #pragma unroll
  for (int i=0;i<8;i++){
    int e = base + i*256 + tid;
    meta[i] = -1;
    val[i] = 0;
    if (e < E){
      int d = ei[E + e];
      int s = ei[e];
      if ((unsigned)d < (unsigned)n && (unsigned)s < (unsigned)n){
        int gf = (int)__umulhi((unsigned)d, magic);   // d/span exact for d < 2^17
        int dl = d - gf*span;
        val[i] = (dl << 17) | s;
        int rank = atomicAdd(&lcnt[gf], 1);           // LDS atomic only
        meta[i] = (gf << 11) | rank;
      }
    }
  }
  __syncthreads();
  int v = lcnt[tid];
  sScan[tid] = v;
  __syncthreads();
  for (int o=1;o<256;o<<=1){
    int t = (tid>=o) ? sScan[tid-o] : 0;
    __syncthreads();
    if (tid>=o) sScan[tid] += t;
    __syncthreads();
  }
  lbase[tid] = sScan[tid] - v;
  if (tid == 255) lbase[NGF] = sScan[255];
  __syncthreads();
  #pragma unroll
  for (int i=0;i<8;i++){
    if (meta[i] >= 0){
      int gf   = meta[i] >> 11;
      int rank = meta[i] & 0x7FF;
      sStage[lbase[gf] + rank] = val[i];
    }
  }
  int* row = lbasemat + (size_t)blockIdx.x*(NGF+1);
  row[tid] = lbase[tid];
  if (tid == 0) row[NGF] = lbase[NGF];
  __syncthreads();
  int* bp = bucket + (size_t)blockIdx.x*2048;
  #pragma unroll
  for (int i=0;i<2;i++){
    int idx = i*256 + tid;
    ((int4*)bp)[idx] = ((const int4*)sStage)[idx];
  }
}

__global__ __launch_bounds__(256) void k_rtot(const int* __restrict__ lbasemat,
                                              int* __restrict__ rt, int nb){
  __shared__ int red[256];
  int gf = blockIdx.x, tid = threadIdx.x;
  int s = 0;
  for (int b=tid; b<nb; b+=256){
    const int* row = lbasemat + (size_t)b*(NGF+1) + gf;
    s += row[1] - row[0];
  }
  red[tid] = s;
  __syncthreads();
  for (int o=128;o>0;o>>=1){
    if (tid < o) red[tid] += red[tid+o];
    __syncthreads();
  }
  if (tid == 0) rt[gf] = red[0];
}

__global__ void k_rscan(const int* __restrict__ rt, int* __restrict__ rbase,
                        int* __restrict__ offsN){
  __shared__ int sc[256];
  int tid = threadIdx.x;
  int v = rt[tid];
  sc[tid] = v;
  __syncthreads();
  for (int o=1;o<256;o<<=1){
    int t = (tid>=o) ? sc[tid-o] : 0;
    __syncthreads();
    if (tid>=o) sc[tid] += t;
    __syncthreads();
  }
  rbase[tid] = sc[tid] - v;
  if (tid == 255){ rbase[NGF] = sc[255]; offsN[0] = sc[255]; }
}

__global__ __launch_bounds__(256) void k_fill3(const int* __restrict__ bucket,
    const int* __restrict__ lbasemat, const int* __restrict__ rbase,
    int* __restrict__ csr, int* __restrict__ offs, float* __restrict__ invdeg,
    int n, int span, int nb){
  __shared__ int sLo[NBMAX];
  __shared__ int sPre[NBMAX+1];
  __shared__ int sScan[256];
  __shared__ int sHist[512];
  __shared__ int sCur[512];
  int gf = blockIdx.x, tid = threadIdx.x;
  for (int b=tid; b<nb; b+=256){
    const int* row = lbasemat + (size_t)b*(NGF+1) + gf;
    int lo = row[0], hi = row[1];
    sLo[b]  = b*2048 + lo;
    sPre[b] = hi - lo;
  }
  for (int t=tid; t<512; t+=256){ sHist[t] = 0; }
  __syncthreads();
  int C = (nb + 255) >> 8;
  int st = tid*C, en = st + C; if (en > nb) en = nb; if (st > nb) st = nb;
  int a0 = 0;
  for (int i=st;i<en;i++) a0 += sPre[i];
  sScan[tid] = a0;
  __syncthreads();
  for (int o=1;o<256;o<<=1){
    int t = (tid>=o) ? sScan[tid-o] : 0;
    __syncthreads();
    if (tid>=o) sScan[tid] += t;
    __syncthreads();
  }
  int ex = sScan[tid] - a0;
  int run = ex;
  for (int i=st;i<en;i++){ int t = sPre[i]; sPre[i] = run; run += t; }
  if (tid == 255) sPre[nb] = sScan[255];
  __syncthreads();
  int total = sPre[nb];
  int rb = rbase[gf];
  for (int i=tid; i<total; i+=256){
    int lo = 0, hi = nb;
    while (hi - lo > 1){ int mid = (lo+hi) >> 1; if (sPre[mid] <= i) lo = mid; else hi = mid; }
    int v = bucket[sLo[lo] + (i - sPre[lo])];
    atomicAdd(&sHist[v >> 17], 1);
  }
  __syncthreads();
  int C2 = (span + 255) >> 8;
  int st2 = tid*C2, en2 = st2 + C2; if (en2 > span) en2 = span; if (st2 > span) st2 = span;
  int a2 = 0;
  for (int i=st2;i<en2;i++) a2 += sHist[i];
  sScan[tid] = a2;
  __syncthreads();
  for (int o=1;o<256;o<<=1){
    int t = (tid>=o) ? sScan[tid-o] : 0;
    __syncthreads();
    if (tid>=o) sScan[tid] += t;
    __syncthreads();
  }
  int ex2 = sScan[tid] - a2;
  int run2 = ex2;
  for (int i=st2;i<en2;i++){ sCur[i] = run2; run2 += sHist[i]; }
  __syncthreads();
  for (int t=tid; t<span; t+=256){
    int node = gf*span + t;
    if (node < n){
      int deg = sHist[t];
      offs[node]   = rb + sCur[t];
      invdeg[node] = (deg > 0) ? 1.0f/(float)deg : 0.0f;
    }
  }
  __syncthreads();
  for (int i=tid; i<total; i+=256){
    int lo = 0, hi = nb;
    while (hi - lo > 1){ int mid = (lo+hi) >> 1; if (sPre[mid] <= i) lo = mid; else hi = mid; }
    int v  = bucket[sLo[lo] + (i - sPre[lo])];
    int dl = v >> 17;
    int sc = v & 0x1FFFF;
    int pos = atomicAdd(&sCur[dl], 1);
    csr[rb + pos] = sc;
  }
}

// ---------------- k_sort2: per-region, sort edges by src-tile (TS=1024 -> shifts).
//  csr slice is contiguous and dst-sorted; dl recovered by binary search on offs. ----------------

__global__ __launch_bounds__(256) void k_sort2(const int* __restrict__ csr,
    const int* __restrict__ offs, const int* __restrict__ rbase,
    int* __restrict__ e2, int* __restrict__ toffs, int n, int span, int nt){
  __shared__ int soffs[SPANMAX+1];
  __shared__ int hist[NT_MAX];
  __shared__ int cur[NT_MAX];
  __shared__ int sScan[256];
  int r = blockIdx.x, tid = threadIdx.x;
  int rlo = r*span;
  if (rlo >= n) return;
  int span_r = n - rlo; if (span_r > span) span_r = span;
  int rb = rbase[r], re = rbase[r+1];
  for (int i = tid; i <= span_r; i += 256) soffs[i] = offs[rlo + i];
  for (int t = tid; t < nt; t += 256) hist[t] = 0;
  __syncthreads();
  int total = re - rb;
  for (int i = tid; i < total; i += 256){
    int s = csr[rb + i];
    atomicAdd(&hist[s >> 10], 1);
  }
  __syncthreads();
  int v = (tid < nt) ? hist[tid] : 0;
  sScan[tid] = v;
  __syncthreads();
  for (int o=1;o<256;o<<=1){
    int t = (tid>=o) ? sScan[tid-o] : 0;
    __syncthreads();
    if (tid>=o) sScan[tid] += t;
    __syncthreads();
  }
  if (tid < nt){
    cur[tid] = sScan[tid] - v;
    toffs[r*(nt+1)+tid] = rb + sScan[tid] - v;
  }
  if (tid == 0) toffs[r*(nt+1)+nt] = re;
  __syncthreads();
  for (int i = tid; i < total; i += 256){
    int gi = rb + i;
    int s = csr[gi];
    int lo = 0, hi = span_r;
    while (hi - lo > 1){ int mid=(lo+hi)>>1; if (soffs[mid] <= gi) lo = mid; else hi = mid; }
    int pos = atomicAdd(&cur[s >> 10], 1);
    e2[rb + pos] = (lo << 10) | (s & 1023);   // dl<512 (9b) | src%TS (10b)
  }
}

// ---------------- proj_in: unchanged math; writes fp8 in TWO 16B PLANES ----------------
// plane0 = features 0..15 at uout[node*16]; plane1 = features 16..31 at uout[n*16 + node*16]

__global__ __launch_bounds__(256) void k_in(const float* __restrict__ x, unsigned char* __restrict__ uout,
    const int* __restrict__ offs, const int* __restrict__ csr, const float* __restrict__ invdeg,
    const float* __restrict__ A, const float* __restrict__ B, int n){
  __shared__ float sA[128], sB[128];
  int tid = threadIdx.x;
  if (tid < 128){ sA[tid]=A[tid]; sB[tid]=B[tid]; }
  __syncthreads();
  int node = blockIdx.x*256 + tid;
  if (node >= n) return;
  float4 s = {0,0,0,0};
  int b0=offs[node], e0=offs[node+1];
  for (int k=b0;k<e0;k++){
    int sid = csr[k];
    float4 v = ((const float4*)x)[sid];
    s.x+=v.x; s.y+=v.y; s.z+=v.z; s.w+=v.w;
  }
  float idg = invdeg[node];
  s.x*=idg; s.y*=idg; s.z*=idg; s.w*=idg;
  float4 xr = ((const float4*)x)[node];
  float z[32];
  #pragma unroll
  for (int j=0;j<32;j++){
    z[j] = s.x*sA[j] + s.y*sA[32+j] + s.z*sA[64+j] + s.w*sA[96+j]
         + xr.x*sB[j] + xr.y*sB[32+j] + xr.z*sB[64+j] + xr.w*sB[96+j];
  }
  float m = z[0];
  #pragma unroll
  for (int j=1;j<32;j++) m = fmaxf(m,z[j]);
  float sum=0.0f;
  #pragma unroll
  for (int j=0;j<32;j++){ z[j]=expf(z[j]-m); sum+=z[j]; }
  float r = 1.0f/sum;
  unsigned pk[8];
  #pragma unroll
  for (int q=0;q<8;q++){
    int w0 = __builtin_amdgcn_cvt_pk_fp8_f32(z[4*q]*r,   z[4*q+1]*r, 0,  false);
    w0     = __builtin_amdgcn_cvt_pk_fp8_f32(z[4*q+2]*r, z[4*q+3]*r, w0, true);
    pk[q] = (unsigned)w0;
  }
  *(uint4*)(uout + (size_t)node*16)                   = make_uint4(pk[0],pk[1],pk[2],pk[3]);
  *(uint4*)(uout + (size_t)n*16 + (size_t)node*16)    = make_uint4(pk[4],pk[5],pk[6],pk[7]);
}

// ---------------- conv round v3 (stream+scatter, 56.5KB LDS):
//  2 feature-half passes; each streams its plane through a single 16KB LDS tile
//  (reg-prefetch overlap, LDS-only barriers) and scatters f32 into sMsg[span][17];
//  after each pass the owning lane-quads park (msg*invdeg+base)->f16 in registers.
//  Epilogue = proven MFMA/softmax/fp8 math, plane-layout I/O. ----------------

__global__ __launch_bounds__(CONV_T) void k_conv3(
    const unsigned char* __restrict__ uin, unsigned char* __restrict__ uout,
    const int* __restrict__ e2, const int* __restrict__ toffs,
    const float* __restrict__ invdeg,
    const float* __restrict__ Wa, const float* __restrict__ Wb,
    const float* __restrict__ cs_prev, float Rscale, float base,
    float* __restrict__ cs_next, int n, int span, int nt){
  __shared__ float sWa[1024], sWb[1024];       // 8 KB
  __shared__ float sMsg[SPANMAX*17];           // 27.2 KB
  __shared__ uint4 sBuf[TS];                   // 16 KB
  __shared__ unsigned char sU[128][32];        // 4 KB
  __shared__ float sCol[32];
  __shared__ int sToffs[NT_MAX+1];
  int tid = threadIdx.x;
  int r = blockIdx.x;
  int rlo = r*span;
  if (rlo >= n) return;
  int span_r = n - rlo; if (span_r > span) span_r = span;

  if (tid < 256){
    float rcf = 1.0f;
    if (cs_prev) rcf = 131072.0f / ((float)n + cs_prev[(tid>>3)*CSTR]);
    ((f4*)sWa)[tid] = ((const f4*)Wa)[tid] * rcf;
    ((f4*)sWb)[tid] = ((const f4*)Wb)[tid] * rcf;
  }
  for (int t = tid; t <= nt; t += CONV_T) sToffs[t] = toffs[r*(nt+1) + t];
  for (int i = tid; i < SPANMAX*17; i += CONV_T) sMsg[i] = 0.0f;
  if (tid < 32) sCol[tid] = 0.0f;
  __syncthreads();

  int wv   = tid >> 6;
  int lane = tid & 63;
  int q    = lane >> 4;
  int c    = lane & 15;
  int half = wv >> 2;
  int wvl  = wv & 3;

  h8 park[NGG];

  #pragma unroll
  for (int kh = 0; kh < 2; kh++){
    const unsigned char* up = uin + (size_t)kh*((size_t)n*16);
    uint4 st0, st1;
    {
      const uint4* gt = (const uint4*)up;
      st0 = gt[tid]; st1 = gt[CONV_T + tid];
    }
    for (int t = 0; t < nt; t++){
      sBuf[tid] = st0;                 // compiler inserts vmcnt wait for own loads
      sBuf[CONV_T + tid] = st1;
      if (t+1 < nt){
        const uint4* gt = (const uint4*)(up + (size_t)(t+1)*(TS*16));
        st0 = gt[tid]; st1 = gt[CONV_T + tid];   // tail overrun stays inside workspace
      }
      BAR_LDS();                       // tile visible; prefetch NOT drained
      int eb = sToffs[t], ee = sToffs[t+1];
      const unsigned char* bufc = (const unsigned char*)sBuf;
      for (int e0 = eb + wv*16; e0 < ee; e0 += CONV_T/4){
        int e = e0 + c;
        if (e < ee){
          int v  = e2[e];
          int dl = v >> 10;
          int sl = v & 1023;
          unsigned wbits = *(const unsigned*)(bufc + sl*16 + q*4);
          f4 dv = dec4(wbits);
          float* mrow = &sMsg[dl*17 + q*4];
          atomicAdd(&mrow[0], dv[0]);
          atomicAdd(&mrow[1], dv[1]);
          atomicAdd(&mrow[2], dv[2]);
          atomicAdd(&mrow[3], dv[3]);
        }
      }
      BAR_LDS();                       // scatter done before buffer reuse
    }
    // park this half's fragments: features [kh*16, kh*16+16) live in lanes with q>>1 == kh
    if ((q >> 1) == kh){
      #pragma unroll
      for (int gg = 0; gg < NGG; gg++){
        int dl_in = gg*128 + half*64 + wvl*16 + c;
        f8 a0 = {0,0,0,0,0,0,0,0};
        if (dl_in < span_r){
          float idg = invdeg[rlo + dl_in];
          #pragma unroll
          for (int j=0;j<8;j++) a0[j] = sMsg[dl_in*17 + (q&1)*8 + j];
          float bavg = (idg != 0.0f) ? base : 0.0f;
          a0 = a0*idg + bavg;
        }
        park[gg] = __builtin_convertvector(a0, h8);
      }
    }
    __syncthreads();                   // parks (LDS reads) done
    if (kh == 0){
      for (int i = tid; i < SPANMAX*17; i += CONV_T) sMsg[i] = 0.0f;
      // zeros made visible by pass-1 tile-0 BAR_LDS (lgkmcnt0 + barrier)
    }
  }

  // ---- epilogue: MFMA + row softmax + fp8 encode ----
  h8 waLo, waHi, wbLo, wbHi;
  #pragma unroll
  for (int j=0;j<8;j++){
    int k = q*8 + j;
    waLo[j] = (_Float16)sWa[k*32 + c];
    waHi[j] = (_Float16)sWa[k*32 + c + 16];
    wbLo[j] = (_Float16)sWb[k*32 + c];
    wbHi[j] = (_Float16)sWb[k*32 + c + 16];
  }
  const unsigned char* up0 = uin;
  const unsigned char* up1 = uin + (size_t)n*16;
  #pragma unroll
  for (int gg = 0; gg < NGG; gg++){
    int sb = gg*128 + half*64 + wvl*16;
    int dl_in = sb + c;
    int node  = rlo + dl_in;
    bool gv = (dl_in < span_r);
    h8 afrag = park[gg];
    f8 od = {0,0,0,0,0,0,0,0};
    if (gv){
      const unsigned char* rp = (q & 2) ? up1 : up0;
      uint2 w = *(const uint2*)(rp + (size_t)node*16 + (size_t)(q&1)*8);
      od = dec8(w) + base;
    }
    h8 ofrag = __builtin_convertvector(od, h8);

    f4 z1 = {0,0,0,0}, z2 = {0,0,0,0};
    z1 = __builtin_amdgcn_mfma_f32_16x16x32_f16(ofrag, wbLo, z1, 0, 0, 0);
    z1 = __builtin_amdgcn_mfma_f32_16x16x32_f16(afrag, waLo, z1, 0, 0, 0);
    z2 = __builtin_amdgcn_mfma_f32_16x16x32_f16(ofrag, wbHi, z2, 0, 0, 0);
    z2 = __builtin_amdgcn_mfma_f32_16x16x32_f16(afrag, waHi, z2, 0, 0, 0);
    z1 *= Rscale; z2 *= Rscale;

    f4 mx, sm;
    #pragma unroll
    for (int rr=0;rr<4;rr++) mx[rr] = fmaxf(z1[rr], z2[rr]);
    #pragma unroll
    for (int s=1;s<16;s<<=1){
      #pragma unroll
      for (int rr=0;rr<4;rr++) mx[rr] = fmaxf(mx[rr], __shfl_xor(mx[rr], s));
    }
    #pragma unroll
    for (int rr=0;rr<4;rr++){
      z1[rr] = expf(z1[rr]-mx[rr]);
      z2[rr] = expf(z2[rr]-mx[rr]);
      sm[rr] = z1[rr] + z2[rr];
    }
    #pragma unroll
    for (int s=1;s<16;s<<=1){
      #pragma unroll
      for (int rr=0;rr<4;rr++) sm[rr] += __shfl_xor(sm[rr], s);
    }
    float cs1 = 0.0f, cs2 = 0.0f;
    #pragma unroll
    for (int rr=0;rr<4;rr++){
      float rs = 1.0f/sm[rr];
      float v1 = expf(z1[rr]*rs) - 1.0f;   // store v = u - 1 (fp8-friendly)
      float v2 = expf(z2[rr]*rs) - 1.0f;
      int p1 = __builtin_amdgcn_cvt_pk_fp8_f32(v1, v1, 0, false);
      int p2 = __builtin_amdgcn_cvt_pk_fp8_f32(v2, v2, 0, false);
      f2 d1 = __builtin_amdgcn_cvt_pk_f32_fp8(p1, false);
      f2 d2 = __builtin_amdgcn_cvt_pk_f32_fp8(p2, false);
      int lrow = half*64 + wvl*16 + q*4 + rr;
      sU[lrow][c]      = (unsigned char)(p1 & 0xff);
      sU[lrow][c + 16] = (unsigned char)(p2 & 0xff);
      if (sb + q*4 + rr < span_r){
        cs1 += d1[0];
        cs2 += d2[0];
      }
    }
    cs1 += __shfl_xor(cs1, 16); cs1 += __shfl_xor(cs1, 32);
    cs2 += __shfl_xor(cs2, 16); cs2 += __shfl_xor(cs2, 32);
    if (lane < 16){
      atomicAdd(&sCol[c],      cs1);
      atomicAdd(&sCol[c + 16], cs2);
    }
    __syncthreads();
    // plane-layout writeout: 8B/lane
    int row = tid >> 2;
    int jj  = tid & 3;
    int dlw = gg*128 + row;
    if (dlw < span_r){
      uint2 val = *(const uint2*)&sU[row][jj*8];
      unsigned char* dst = uout + (size_t)(jj>>1)*((size_t)n*16)
                                + (size_t)(rlo+dlw)*16 + (size_t)(jj&1)*8;
      *(uint2*)dst = val;
    }
    __syncthreads();
  }
  if (tid < 32) atomicAdd(&cs_next[tid*CSTR], sCol[tid]);
}

// ---------------- output layer (plane reads) ----------------

__global__ __launch_bounds__(256) void k_out1(const unsigned char* __restrict__ u, const float* __restrict__ W,
    const float* __restrict__ bptr, const float* __restrict__ cs_last,
    float* __restrict__ z, unsigned* __restrict__ zmaxkey, int n){
  __shared__ float ws[32];
  __shared__ float red[256];
  int tid = threadIdx.x;
  if (tid < 32) ws[tid] = W[tid] * (1.0f / ((float)n + cs_last[tid*CSTR]));
  __syncthreads();
  float sws = 0.0f;
  #pragma unroll
  for (int j=0;j<32;j++) sws += ws[j];
  int node = blockIdx.x*256 + tid;
  float zz = -3.0e38f;
  if (node < n){
    float acc = bptr[0] + sws;
    uint4 w0 = *(const uint4*)(u + (size_t)node*16);
    uint4 w1 = *(const uint4*)(u + (size_t)n*16 + (size_t)node*16);
    unsigned wd[8] = {w0.x,w0.y,w0.z,w0.w,w1.x,w1.y,w1.z,w1.w};
    #pragma unroll
    for (int q=0;q<8;q++){
      f4 a = dec4(wd[q]);
      f4 w = ((const f4*)ws)[q];
      acc += a[0]*w[0] + a[1]*w[1] + a[2]*w[2] + a[3]*w[3];
    }
    z[node]=acc; zz=acc;
  }
  red[tid]=zz; __syncthreads();
  for (int s=128;s>0;s>>=1){
    if (tid<s) red[tid]=fmaxf(red[tid],red[tid+s]);
    __syncthreads();
  }
  if (tid==0) atomicMax(zmaxkey, f2key(red[0]));
}

__global__ __launch_bounds__(256) void k_out2(const float* __restrict__ z, const unsigned* __restrict__ zmaxkey,
                                              float* __restrict__ zsum, int n){
  __shared__ float red[256];
  int tid = threadIdx.x;
  int node = blockIdx.x*256 + tid;
  float zmax = key2f(*zmaxkey);
  float v = (node<n) ? expf(z[node]-zmax) : 0.0f;
  red[tid]=v; __syncthreads();
  for (int s=128;s>0;s>>=1){
    if (tid<s) red[tid]+=red[tid+s];
    __syncthreads();
  }
  if (tid==0) atomicAdd(zsum, red[0]);
}

__global__ __launch_bounds__(256) void k_out3(const float* __restrict__ z, const unsigned* __restrict__ zmaxkey,
                                              const float* __restrict__ zsum, float* __restrict__ out, int n){
  int node = blockIdx.x*256 + threadIdx.x;
  if (node < n){
    float zmax = key2f(*zmaxkey);
    out[node] = expf(z[node]-zmax) / (*zsum);
  }
}

// ---------------- host launcher ----------------

extern "C" void kernel_launch(void* const* d_in, const int* in_sizes, int n_in,
                              void* d_out, int out_size, void* d_ws, size_t ws_size,
                              hipStream_t stream) {
  const float* x      = (const float*)d_in[0];
  const int*   ei     = (const int*)d_in[1];
  const float* A_in   = (const float*)d_in[2];
  const float* B_in   = (const float*)d_in[3];
  const float* A_conv = (const float*)d_in[4];
  const float* B_conv = (const float*)d_in[5];
  const float* W_out  = (const float*)d_in[6];
  const float* b_out  = (const float*)d_in[7];
  const int N = in_sizes[0] / 4;
  const int E = in_sizes[1] / 2;
  const int NROUNDS = 16;

  char* w = (char*)d_ws;
  size_t o = 0;
  auto alloc = [&](size_t bytes)->char* {
    char* p = w + o;
    o = (o + bytes + 15) & ~(size_t)15;
    return p;
  };
  // ---- zero-init control region (one memset) ----
  float*    colsum  = (float*)   alloc((size_t)NROUNDS*32*CSTR*4);
  unsigned* zmaxkey = (unsigned*)alloc(4);
  float*    zsum    = (float*)   alloc(4);
  size_t ctrl_bytes = o;
  // ---- rest (fully written before read) ----
  int    nb      = (E + 2047) / 2048;          // <= NBMAX
  int    span    = (N + NGF - 1) / NGF;        // <= SPANMAX for N <= 102400
  int    nt      = (N + TS - 1) / TS;          // <= NT_MAX
  int*   offs    = (int*)  alloc((size_t)(N+1)*4);
  float* invdeg  = (float*)alloc((size_t)N*4);
  int*   csr     = (int*)  alloc((size_t)E*4);
  int*   bucket  = (int*)  alloc((size_t)nb*2048*4);   // reused as e2 after k_fill3
  int*   lbasemat= (int*)  alloc((size_t)nb*(NGF+1)*4);// reused as toffs after k_fill3
  int*   rt      = (int*)  alloc((size_t)NGF*4);
  int*   rbase   = (int*)  alloc((size_t)(NGF+1)*4);
  unsigned char* uA = (unsigned char*)alloc((size_t)N*32);
  unsigned char* uB = (unsigned char*)alloc((size_t)N*32);
  float* zbuf    = (float*)alloc((size_t)N*4);          // also absorbs conv3 tile-tail overrun
  (void)ws_size; (void)n_in; (void)out_size;

  hipMemsetAsync(d_ws, 0, ctrl_bytes, stream);

  unsigned magic = (unsigned)((((unsigned long long)1 << 32) + (unsigned long long)span - 1)
                              / (unsigned long long)span);
  int gridN = (N + 255) / 256;
  int*   e2    = bucket;     // safe: k_sort2 reads csr (not bucket), runs after k_fill3
  int*   toffs = lbasemat;   // safe: lbasemat dead after k_fill3

  // CSR build: no per-edge global atomics anywhere
  k_bucketA<<<nb, 256, 0, stream>>>(ei, bucket, lbasemat, E, N, span, magic);
  k_rtot   <<<NGF, 256, 0, stream>>>(lbasemat, rt, nb);
  k_rscan  <<<1, 256, 0, stream>>>(rt, rbase, offs + N);
  k_fill3  <<<NGF, 256, 0, stream>>>(bucket, lbasemat, rbase, csr, offs, invdeg, N, span, nb);
  k_sort2  <<<NGF, 256, 0, stream>>>(csr, offs, rbase, e2, toffs, N, span, nt);

  // proj_in -> p stored fp8, plane layout
  k_in<<<gridN, 256, 0, stream>>>(x, uA, offs, csr, invdeg, A_in, B_in, N);

  // 16 conv rounds (stream+scatter formulation)
  const float R17 = 1.0f/131072.0f;
  for (int r = 0; r < NROUNDS; r++){
    const float* Wa = A_conv + (size_t)r*32*32;
    const float* Wb = B_conv + (size_t)r*32*32;
    const float* cs_prev = (r == 0) ? nullptr : (colsum + (size_t)(r-1)*32*CSTR);
    float*       cs_next = colsum + (size_t)r*32*CSTR;
    float        Rs      = (r == 0) ? 1.0f : R17;
    float        base    = (r == 0) ? 0.0f : 1.0f;
    const unsigned char* ui = (r & 1) ? uB : uA;
    unsigned char*       uo = (r & 1) ? uA : uB;
    k_conv3<<<NGF, CONV_T, 0, stream>>>(ui, uo, e2, toffs, invdeg, Wa, Wb, cs_prev, Rs, base, cs_next, N, span, nt);
  }

  // output layer
  k_out1<<<gridN, 256, 0, stream>>>(uA, W_out, b_out, colsum + (size_t)(NROUNDS-1)*32*CSTR, zbuf, zmaxkey, N);
  k_out2<<<gridN, 256, 0, stream>>>(zbuf, zmaxkey, zsum, N);
  k_out3<<<gridN, 256, 0, stream>>>(zbuf, zmaxkey, zsum, (float*)d_out, N);
}

// Round 5
// 955.779 us; speedup vs baseline: 10.9498x; 10.9498x over previous
//
#include <hip/hip_runtime.h>

#define NGF 256     // dst-regions (span = ceil(N/256) <= 512)
#define BAE 8192    // edges per bucketA block (runs avg ~32 edges = 1 cache line)
#define BAVPT 32    // BAE/256
#define CSTR 64     // colsum element stride (256B) -> spread across L2 slices

typedef float    f2 __attribute__((ext_vector_type(2)));
typedef float    f4 __attribute__((ext_vector_type(4)));
typedef float    f8 __attribute__((ext_vector_type(8)));
typedef _Float16 h8 __attribute__((ext_vector_type(8)));

__device__ __forceinline__ unsigned f2key(float x){
  unsigned b = __float_as_uint(x);
  return (b & 0x80000000u) ? ~b : (b | 0x80000000u);
}
__device__ __forceinline__ float key2f(unsigned k){
  return (k & 0x80000000u) ? __uint_as_float(k ^ 0x80000000u) : __uint_as_float(~k);
}

// fp8 e4m3 HW decode: 4 bytes -> 4 floats
__device__ __forceinline__ f4 dec4(unsigned w){
  f2 a = __builtin_amdgcn_cvt_pk_f32_fp8((int)w, false);
  f2 b = __builtin_amdgcn_cvt_pk_f32_fp8((int)w, true);
  f4 r; r[0]=a[0]; r[1]=a[1]; r[2]=b[0]; r[3]=b[1];
  return r;
}
__device__ __forceinline__ f8 dec8(uint2 w){
  f4 lo = dec4(w.x), hi = dec4(w.y);
  f8 r;
  r[0]=lo[0]; r[1]=lo[1]; r[2]=lo[2]; r[3]=lo[3];
  r[4]=hi[0]; r[5]=hi[1]; r[6]=hi[2]; r[7]=hi[3];
  return r;
}

// ---------------- CSR build v3: zero per-edge global atomics; 8192-edge bucket
//  blocks (runs ~1 line) + transposed run-descriptor matrix + run-major fill
//  (no per-edge binary search). ----------------
// pack: val = (dl<<17)|src  (dl < 512, src < 131072); meta = (gf<<13)|rank (rank < 8192)

__global__ __launch_bounds__(256) void k_bucketA(const int* __restrict__ ei,
    int* __restrict__ bucket, int* __restrict__ lbasemat,
    int E, int n, int span, unsigned magic){
  __shared__ int lcnt[NGF];
  __shared__ int lbase[NGF+1];
  __shared__ int sStage[BAE];
  __shared__ int sScan[256];
  int tid = threadIdx.x;
  lcnt[tid] = 0;
  __syncthreads();
  int base = blockIdx.x*BAE;
  int val[BAVPT], meta[BAVPT];
  #pragma unroll
  for (int i=0;i<BAVPT;i++){
    int e = base + i*256 + tid;
    meta[i] = -1;
    val[i] = 0;
    if (e < E){
      int d = ei[E + e];
      int s = ei[e];
      if ((unsigned)d < (unsigned)n && (unsigned)s < (unsigned)n){
        int gf = (int)__umulhi((unsigned)d, magic);   // d/span exact for d < 2^17
        int dl = d - gf*span;
        val[i] = (dl << 17) | s;
        int rank = atomicAdd(&lcnt[gf], 1);           // LDS atomic only
        meta[i] = (gf << 13) | rank;
      }
    }
  }
  __syncthreads();
  int v = lcnt[tid];
  sScan[tid] = v;
  __syncthreads();
  for (int o=1;o<256;o<<=1){
    int t = (tid>=o) ? sScan[tid-o] : 0;
    __syncthreads();
    if (tid>=o) sScan[tid] += t;
    __syncthreads();
  }
  lbase[tid] = sScan[tid] - v;
  if (tid == 255) lbase[NGF] = sScan[255];
  __syncthreads();
  #pragma unroll
  for (int i=0;i<BAVPT;i++){
    if (meta[i] >= 0){
      int gf   = meta[i] >> 13;
      int rank = meta[i] & 0x1FFF;
      sStage[lbase[gf] + rank] = val[i];
    }
  }
  int* row = lbasemat + (size_t)blockIdx.x*(NGF+1);
  row[tid] = lbase[tid];
  if (tid == 0) row[NGF] = lbase[NGF];
  __syncthreads();
  int* bp = bucket + (size_t)blockIdx.x*BAE;
  #pragma unroll
  for (int i=0;i<BAE/1024;i++){
    int idx = i*256 + tid;
    ((int4*)bp)[idx] = ((const int4*)sStage)[idx];   // slots beyond count: garbage, never read
  }
}

// transpose lbasemat[nb][NGF+1] -> lbT[NGF+1][nbp] so fill/rtot read runs contiguously
__global__ __launch_bounds__(1024) void k_transp(const int* __restrict__ in,
    int* __restrict__ out, int nb, int nbp){
  __shared__ int t[32][33];
  int bx = blockIdx.x*32, by = blockIdx.y*32;
  int tx = threadIdx.x, ty = threadIdx.y;
  int b = bx + ty;
  int g = by + tx;
  if (b < nb && g < NGF+1) t[ty][tx] = in[(size_t)b*(NGF+1) + g];
  __syncthreads();
  int g2 = by + ty;
  int b2 = bx + tx;
  if (g2 < NGF+1 && b2 < nb) out[(size_t)g2*nbp + b2] = t[tx][ty];
}

__global__ __launch_bounds__(256) void k_rtot(const int* __restrict__ lbT,
                                              int* __restrict__ rt, int nb, int nbp){
  __shared__ int red[256];
  int gf = blockIdx.x, tid = threadIdx.x;
  const int* lo = lbT + (size_t)gf*nbp;
  const int* hi = lo + nbp;
  int s = 0;
  for (int b=tid; b<nb; b+=256) s += hi[b] - lo[b];
  red[tid] = s;
  __syncthreads();
  for (int o=128;o>0;o>>=1){
    if (tid < o) red[tid] += red[tid+o];
    __syncthreads();
  }
  if (tid == 0) rt[gf] = red[0];
}

__global__ void k_rscan(const int* __restrict__ rt, int* __restrict__ rbase,
                        int* __restrict__ offsN){
  __shared__ int sc[256];
  int tid = threadIdx.x;
  int v = rt[tid];
  sc[tid] = v;
  __syncthreads();
  for (int o=1;o<256;o<<=1){
    int t = (tid>=o) ? sc[tid-o] : 0;
    __syncthreads();
    if (tid>=o) sc[tid] += t;
    __syncthreads();
  }
  rbase[tid] = sc[tid] - v;
  if (tid == 255){ rbase[NGF] = sc[255]; offsN[0] = sc[255]; }
}

// run-major fill: thread = run (32-edge avg, 1 line), no binary search
__global__ __launch_bounds__(256) void k_fill4(const int* __restrict__ bucket,
    const int* __restrict__ lbT, const int* __restrict__ rbase,
    int* __restrict__ csr, int* __restrict__ offs, float* __restrict__ invdeg,
    int n, int span, int nb, int nbp){
  __shared__ int sHist[512];
  __shared__ int sCur[512];
  __shared__ int sScan[256];
  int gf = blockIdx.x, tid = threadIdx.x;
  int rb = rbase[gf];
  const int* rowLo = lbT + (size_t)gf*nbp;
  const int* rowHi = rowLo + nbp;
  for (int i=tid; i<512; i+=256) sHist[i] = 0;
  __syncthreads();
  // pass 1: run-major histogram
  for (int b=tid; b<nb; b+=256){
    int lo = rowLo[b], hi = rowHi[b];
    const int* bp = bucket + (size_t)b*BAE;
    for (int i=lo; i<hi; i++)
      atomicAdd(&sHist[((unsigned)bp[i]) >> 17], 1);
  }
  __syncthreads();
  // node-prefix scan (span <= 512)
  int C2 = (span + 255) >> 8;
  int st2 = tid*C2, en2 = st2 + C2; if (en2 > span) en2 = span; if (st2 > span) st2 = span;
  int a2 = 0;
  for (int i=st2;i<en2;i++) a2 += sHist[i];
  sScan[tid] = a2;
  __syncthreads();
  for (int o=1;o<256;o<<=1){
    int t = (tid>=o) ? sScan[tid-o] : 0;
    __syncthreads();
    if (tid>=o) sScan[tid] += t;
    __syncthreads();
  }
  int ex2 = sScan[tid] - a2;
  int run2 = ex2;
  for (int i=st2;i<en2;i++){ sCur[i] = run2; run2 += sHist[i]; }
  __syncthreads();
  for (int t=tid; t<span; t+=256){
    int node = gf*span + t;
    if (node < n){
      int deg = sHist[t];
      offs[node]   = rb + sCur[t];
      invdeg[node] = (deg > 0) ? 1.0f/(float)deg : 0.0f;  // 0 marks isolated node
    }
  }
  __syncthreads();
  // pass 2: run-major place (csr writes land in region's ~50KB L2-resident window)
  for (int b=tid; b<nb; b+=256){
    int lo = rowLo[b], hi = rowHi[b];
    const int* bp = bucket + (size_t)b*BAE;
    for (int i=lo; i<hi; i++){
      int v = bp[i];
      int pos = atomicAdd(&sCur[((unsigned)v) >> 17], 1);
      csr[rb + pos] = v & 0x1FFFF;
    }
  }
}

// ---------------- proj_in: gather x[4] + (avg@A + x@B) + row softmax -> fp8 (base 0) ----------------

__global__ __launch_bounds__(256) void k_in(const float* __restrict__ x, unsigned char* __restrict__ uout,
    const int* __restrict__ offs, const int* __restrict__ csr, const float* __restrict__ invdeg,
    const float* __restrict__ A, const float* __restrict__ B, int n){
  __shared__ float sA[128], sB[128];
  int tid = threadIdx.x;
  if (tid < 128){ sA[tid]=A[tid]; sB[tid]=B[tid]; }
  __syncthreads();
  int node = blockIdx.x*256 + tid;
  if (node >= n) return;
  float4 s = {0,0,0,0};
  int b0=offs[node], e0=offs[node+1];
  for (int k=b0;k<e0;k++){
    int sid = csr[k];
    float4 v = ((const float4*)x)[sid];
    s.x+=v.x; s.y+=v.y; s.z+=v.z; s.w+=v.w;
  }
  float idg = invdeg[node];
  s.x*=idg; s.y*=idg; s.z*=idg; s.w*=idg;
  float4 xr = ((const float4*)x)[node];
  float z[32];
  #pragma unroll
  for (int j=0;j<32;j++){
    z[j] = s.x*sA[j] + s.y*sA[32+j] + s.z*sA[64+j] + s.w*sA[96+j]
         + xr.x*sB[j] + xr.y*sB[32+j] + xr.z*sB[64+j] + xr.w*sB[96+j];
  }
  float m = z[0];
  #pragma unroll
  for (int j=1;j<32;j++) m = fmaxf(m,z[j]);
  float sum=0.0f;
  #pragma unroll
  for (int j=0;j<32;j++){ z[j]=expf(z[j]-m); sum+=z[j]; }
  float r = 1.0f/sum;
  unsigned pk[8];
  #pragma unroll
  for (int q=0;q<8;q++){
    int w0 = __builtin_amdgcn_cvt_pk_fp8_f32(z[4*q]*r,   z[4*q+1]*r, 0,  false);
    w0     = __builtin_amdgcn_cvt_pk_fp8_f32(z[4*q+2]*r, z[4*q+3]*r, w0, true);
    pk[q] = (unsigned)w0;
  }
  uint4* op = (uint4*)(uout + (size_t)node*32);
  op[0] = make_uint4(pk[0],pk[1],pk[2],pk[3]);
  op[1] = make_uint4(pk[4],pk[5],pk[6],pk[7]);
}

// ---------------- conv round (MFMA, fp8 state): PROVEN gather form. wave = 16 nodes.
//  Structural floor: one random 32B row-request per edge ~ 50us/round. ----------------

__global__ __launch_bounds__(256) void k_conv(
    const unsigned char* __restrict__ uin, unsigned char* __restrict__ uout,
    const int* __restrict__ offs, const int* __restrict__ csr,
    const float* __restrict__ invdeg,
    const float* __restrict__ Wa, const float* __restrict__ Wb,
    const float* __restrict__ cs_prev, float Rscale, float base,
    float* __restrict__ cs_next, int n){
  __shared__ float sWa[1024], sWb[1024];
  __shared__ float sCol[32];
  __shared__ unsigned char sU[64][32];
  int tid = threadIdx.x;
  float rcf = 1.0f;
  if (cs_prev) rcf = 131072.0f / ((float)n + cs_prev[(tid>>3)*CSTR]);  // rho = 2^17/colsum
  ((f4*)sWa)[tid] = ((const f4*)Wa)[tid] * rcf;
  ((f4*)sWb)[tid] = ((const f4*)Wb)[tid] * rcf;
  if (tid < 32) sCol[tid] = 0.0f;
  __syncthreads();

  int lane = tid & 63;
  int wv   = tid >> 6;
  int q    = lane >> 4;         // k-chunk (A) / row-quad (C)
  int c    = lane & 15;         // gather node (A's m) / output column (B's n, C's col)
  int tile = blockIdx.x*64 + wv*16;
  int node = tile + c;
  bool gv = node < n;

  h8 waLo, waHi, wbLo, wbHi;
  #pragma unroll
  for (int j=0;j<8;j++){
    int k = q*8 + j;
    waLo[j] = (_Float16)sWa[k*32 + c];
    waHi[j] = (_Float16)sWa[k*32 + c + 16];
    wbLo[j] = (_Float16)sWb[k*32 + c];
    wbHi[j] = (_Float16)sWb[k*32 + c + 16];
  }

  f8 a0 = {0,0,0,0,0,0,0,0}, a1 = {0,0,0,0,0,0,0,0};
  f8 a2 = {0,0,0,0,0,0,0,0}, a3 = {0,0,0,0,0,0,0,0};
  int b0 = gv ? offs[node]   : 0;
  int e0 = gv ? offs[node+1] : 0;
  const uint2* ub = (const uint2*)uin;
  int k = b0;
  for (; k+8<=e0; k+=8){
    int s0=csr[k],   s1=csr[k+1], s2=csr[k+2], s3=csr[k+3];
    int s4=csr[k+4], s5=csr[k+5], s6=csr[k+6], s7=csr[k+7];
    uint2 v0 = ub[(size_t)s0*4 + q];
    uint2 v1 = ub[(size_t)s1*4 + q];
    uint2 v2 = ub[(size_t)s2*4 + q];
    uint2 v3 = ub[(size_t)s3*4 + q];
    uint2 v4 = ub[(size_t)s4*4 + q];
    uint2 v5 = ub[(size_t)s5*4 + q];
    uint2 v6 = ub[(size_t)s6*4 + q];
    uint2 v7 = ub[(size_t)s7*4 + q];
    a0 += dec8(v0); a1 += dec8(v1); a2 += dec8(v2); a3 += dec8(v3);
    a0 += dec8(v4); a1 += dec8(v5); a2 += dec8(v6); a3 += dec8(v7);
  }
  for (; k<e0; k++) a0 += dec8(ub[(size_t)csr[k]*4 + q]);
  a0 = (a0 + a1) + (a2 + a3);
  float idg = gv ? invdeg[node] : 0.0f;
  float bavg = (idg != 0.0f) ? base : 0.0f;   // ref: isolated node -> avg = 0
  a0 = a0*idg + bavg;
  h8 afrag = __builtin_convertvector(a0, h8);
  f8 od = {0,0,0,0,0,0,0,0};
  if (gv) od = dec8(ub[(size_t)node*4 + q]) + base;
  h8 ofrag = __builtin_convertvector(od, h8);

  f4 z1 = {0,0,0,0}, z2 = {0,0,0,0};
  z1 = __builtin_amdgcn_mfma_f32_16x16x32_f16(ofrag, wbLo, z1, 0, 0, 0);
  z1 = __builtin_amdgcn_mfma_f32_16x16x32_f16(afrag, waLo, z1, 0, 0, 0);
  z2 = __builtin_amdgcn_mfma_f32_16x16x32_f16(ofrag, wbHi, z2, 0, 0, 0);
  z2 = __builtin_amdgcn_mfma_f32_16x16x32_f16(afrag, waHi, z2, 0, 0, 0);
  z1 *= Rscale; z2 *= Rscale;

  f4 mx, sm;
  #pragma unroll
  for (int r=0;r<4;r++) mx[r] = fmaxf(z1[r], z2[r]);
  #pragma unroll
  for (int s=1;s<16;s<<=1){
    #pragma unroll
    for (int r=0;r<4;r++) mx[r] = fmaxf(mx[r], __shfl_xor(mx[r], s));
  }
  #pragma unroll
  for (int r=0;r<4;r++){
    z1[r] = expf(z1[r]-mx[r]);
    z2[r] = expf(z2[r]-mx[r]);
    sm[r] = z1[r] + z2[r];
  }
  #pragma unroll
  for (int s=1;s<16;s<<=1){
    #pragma unroll
    for (int r=0;r<4;r++) sm[r] += __shfl_xor(sm[r], s);
  }
  float cs1 = 0.0f, cs2 = 0.0f;
  #pragma unroll
  for (int r=0;r<4;r++){
    float rs = 1.0f/sm[r];
    float v1 = expf(z1[r]*rs) - 1.0f;   // store v = u - 1, v in [0, 1.72] (fp8-friendly)
    float v2 = expf(z2[r]*rs) - 1.0f;
    int p1 = __builtin_amdgcn_cvt_pk_fp8_f32(v1, v1, 0, false);
    int p2 = __builtin_amdgcn_cvt_pk_fp8_f32(v2, v2, 0, false);
    f2 d1 = __builtin_amdgcn_cvt_pk_f32_fp8(p1, false);
    f2 d2 = __builtin_amdgcn_cvt_pk_f32_fp8(p2, false);
    int lrow = wv*16 + q*4 + r;
    sU[lrow][c]      = (unsigned char)(p1 & 0xff);
    sU[lrow][c + 16] = (unsigned char)(p2 & 0xff);
    if (tile + q*4 + r < n){
      cs1 += d1[0];                 // colsum consistent with stored (rounded) v
      cs2 += d2[0];
    }
  }
  cs1 += __shfl_xor(cs1, 16); cs1 += __shfl_xor(cs1, 32);
  cs2 += __shfl_xor(cs2, 16); cs2 += __shfl_xor(cs2, 32);
  if (lane < 16){
    atomicAdd(&sCol[c],      cs1);
    atomicAdd(&sCol[c + 16], cs2);
  }
  __syncthreads();
  if (tid < 32) atomicAdd(&cs_next[tid*CSTR], sCol[tid]);
  int row = tid >> 2;
  int jj  = tid & 3;
  int gnode = blockIdx.x*64 + row;
  if (gnode < n){
    uint2 val = *(const uint2*)&sU[row][jj*8];
    *(uint2*)(uout + (size_t)gnode*32 + jj*8) = val;
  }
}

// ---------------- output layer: z = (1+v)@ (W/colsum) + b ----------------

__global__ __launch_bounds__(256) void k_out1(const unsigned char* __restrict__ u, const float* __restrict__ W,
    const float* __restrict__ bptr, const float* __restrict__ cs_last,
    float* __restrict__ z, unsigned* __restrict__ zmaxkey, int n){
  __shared__ float ws[32];
  __shared__ float red[256];
  int tid = threadIdx.x;
  if (tid < 32) ws[tid] = W[tid] * (1.0f / ((float)n + cs_last[tid*CSTR]));
  __syncthreads();
  float sws = 0.0f;
  #pragma unroll
  for (int j=0;j<32;j++) sws += ws[j];
  int node = blockIdx.x*256 + tid;
  float zz = -3.0e38f;
  if (node < n){
    float acc = bptr[0] + sws;
    const uint4* ur = (const uint4*)(u + (size_t)node*32);
    uint4 w0 = ur[0], w1 = ur[1];
    unsigned wd[8] = {w0.x,w0.y,w0.z,w0.w,w1.x,w1.y,w1.z,w1.w};
    #pragma unroll
    for (int q=0;q<8;q++){
      f4 a = dec4(wd[q]);
      f4 w = ((const f4*)ws)[q];
      acc += a[0]*w[0] + a[1]*w[1] + a[2]*w[2] + a[3]*w[3];
    }
    z[node]=acc; zz=acc;
  }
  red[tid]=zz; __syncthreads();
  for (int s=128;s>0;s>>=1){
    if (tid<s) red[tid]=fmaxf(red[tid],red[tid+s]);
    __syncthreads();
  }
  if (tid==0) atomicMax(zmaxkey, f2key(red[0]));
}

__global__ __launch_bounds__(256) void k_out2(const float* __restrict__ z, const unsigned* __restrict__ zmaxkey,
                                              float* __restrict__ zsum, int n){
  __shared__ float red[256];
  int tid = threadIdx.x;
  int node = blockIdx.x*256 + tid;
  float zmax = key2f(*zmaxkey);
  float v = (node<n) ? expf(z[node]-zmax) : 0.0f;
  red[tid]=v; __syncthreads();
  for (int s=128;s>0;s>>=1){
    if (tid<s) red[tid]+=red[tid+s];
    __syncthreads();
  }
  if (tid==0) atomicAdd(zsum, red[0]);
}

__global__ __launch_bounds__(256) void k_out3(const float* __restrict__ z, const unsigned* __restrict__ zmaxkey,
                                              const float* __restrict__ zsum, float* __restrict__ out, int n){
  int node = blockIdx.x*256 + threadIdx.x;
  if (node < n){
    float zmax = key2f(*zmaxkey);
    out[node] = expf(z[node]-zmax) / (*zsum);
  }
}

// ---------------- host launcher ----------------

extern "C" void kernel_launch(void* const* d_in, const int* in_sizes, int n_in,
                              void* d_out, int out_size, void* d_ws, size_t ws_size,
                              hipStream_t stream) {
  const float* x      = (const float*)d_in[0];
  const int*   ei     = (const int*)d_in[1];
  const float* A_in   = (const float*)d_in[2];
  const float* B_in   = (const float*)d_in[3];
  const float* A_conv = (const float*)d_in[4];
  const float* B_conv = (const float*)d_in[5];
  const float* W_out  = (const float*)d_in[6];
  const float* b_out  = (const float*)d_in[7];
  const int N = in_sizes[0] / 4;
  const int E = in_sizes[1] / 2;
  const int NROUNDS = 16;

  char* w = (char*)d_ws;
  size_t o = 0;
  auto alloc = [&](size_t bytes)->char* {
    char* p = w + o;
    o = (o + bytes + 15) & ~(size_t)15;
    return p;
  };
  // ---- zero-init control region (one memset) ----
  float*    colsum  = (float*)   alloc((size_t)NROUNDS*32*CSTR*4);
  unsigned* zmaxkey = (unsigned*)alloc(4);
  float*    zsum    = (float*)   alloc(4);
  size_t ctrl_bytes = o;
  // ---- rest (fully written before read; no zeroing needed) ----
  int    nb      = (E + BAE-1) / BAE;          // 8192-edge blocks
  int    span    = (N + NGF - 1) / NGF;        // <= 512 for N <= 131072
  int*   offs    = (int*)  alloc((size_t)(N+1)*4);
  float* invdeg  = (float*)alloc((size_t)N*4);
  int*   csr     = (int*)  alloc((size_t)E*4);
  int*   bucket  = (int*)  alloc((size_t)nb*BAE*4);
  int*   lbasemat= (int*)  alloc((size_t)nb*(NGF+1)*4);
  int*   lbT     = (int*)  alloc((size_t)(NGF+1)*nb*4);
  int*   rt      = (int*)  alloc((size_t)NGF*4);
  int*   rbase   = (int*)  alloc((size_t)(NGF+1)*4);
  unsigned char* uA = (unsigned char*)alloc((size_t)N*32);
  unsigned char* uB = (unsigned char*)alloc((size_t)N*32);
  float* zbuf    = (float*)alloc((size_t)N*4);
  (void)ws_size; (void)n_in; (void)out_size;

  hipMemsetAsync(d_ws, 0, ctrl_bytes, stream);

  unsigned magic = (unsigned)((((unsigned long long)1 << 32) + (unsigned long long)span - 1)
                              / (unsigned long long)span);
  int gridN = (N + 255) / 256;
  int gridC = (N + 63) / 64;

  // CSR build: no per-edge global atomics anywhere; run-major fill
  k_bucketA<<<nb, 256, 0, stream>>>(ei, bucket, lbasemat, E, N, span, magic);
  {
    dim3 tb(32,32);
    dim3 tg((nb + 31)/32, (NGF+1 + 31)/32);
    k_transp<<<tg, tb, 0, stream>>>(lbasemat, lbT, nb, nb);
  }
  k_rtot <<<NGF, 256, 0, stream>>>(lbT, rt, nb, nb);
  k_rscan<<<1, 256, 0, stream>>>(rt, rbase, offs + N);
  k_fill4<<<NGF, 256, 0, stream>>>(bucket, lbT, rbase, csr, offs, invdeg, N, span, nb, nb);

  // proj_in -> p stored fp8 (base 0)
  k_in<<<gridN, 256, 0, stream>>>(x, uA, offs, csr, invdeg, A_in, B_in, N);

  // 16 conv rounds (proven gather form)
  const float R17 = 1.0f/131072.0f;
  for (int r = 0; r < NROUNDS; r++){
    const float* Wa = A_conv + (size_t)r*32*32;
    const float* Wb = B_conv + (size_t)r*32*32;
    const float* cs_prev = (r == 0) ? nullptr : (colsum + (size_t)(r-1)*32*CSTR);
    float*       cs_next = colsum + (size_t)r*32*CSTR;
    float        Rs      = (r == 0) ? 1.0f : R17;
    float        base    = (r == 0) ? 0.0f : 1.0f;
    const unsigned char* ui = (r & 1) ? uB : uA;
    unsigned char*       uo = (r & 1) ? uA : uB;
    k_conv<<<gridC, 256, 0, stream>>>(ui, uo, offs, csr, invdeg, Wa, Wb, cs_prev, Rs, base, cs_next, N);
  }

  // output layer (colsum_16 = n + sum(v); folded into W_out)
  k_out1<<<gridN, 256, 0, stream>>>(uA, W_out, b_out, colsum + (size_t)(NROUNDS-1)*32*CSTR, zbuf, zmaxkey, N);
  k_out2<<<gridN, 256, 0, stream>>>(zbuf, zmaxkey, zsum, N);
  k_out3<<<gridN, 256, 0, stream>>>(zbuf, zmaxkey, zsum, (float*)d_out, N);
}